// Round 16
// baseline (1959.949 us; speedup 1.0000x reference)
//
#include <hip/hip_runtime.h>
#include <math.h>

// LSTM persistent kernel, R16: R15 + gate-pair-major MFMA scheduling so the
// i/f gate activation chains overlap the g/o MFMA drain. One block per
// batch (64 blocks), 512 threads = 8 waves; wave wv owns all 4 gates of
// elements 16wv..16wv+15; in-wave tail; one barrier/step; bias as C operand.
//
// R15 model (981 cy/step): MFMA pipe 518 + VALU 520, overlap only ~57 --
// c-major issue order finishes all 4 accumulators within 3 issues of each
// other, so the whole tail serializes after the last MFMA. R16 issues the
// 8 MFMAs of gates i,f first, then gates g,o, then consumes d0/d1 (retired
// ~155 cy earlier): the i/f sigmoid chains issue on the VALU while d2/d3
// drain the matrix pipe. Dependent-chain spacing stays 2 issues (~39 cy >
// chained-MFMA latency) via pairwise interleave. Cheaper-MFMA routes
// (fp8/MX, i8-split, 32x32) checked and rejected: accuracy or net cycles.
constexpr int Hdim = 128;
constexpr int TMAX = 4096;

typedef _Float16 v8h __attribute__((ext_vector_type(8)));
typedef float v4f __attribute__((ext_vector_type(4)));

#if __has_builtin(__builtin_amdgcn_exp2f)
__device__ __forceinline__ float exp2_fast(float x) {
  return __builtin_amdgcn_exp2f(x);
}
#else
__device__ __forceinline__ float exp2_fast(float x) {
  return __expf(x * 0.6931471805599453f);
}
#endif

__device__ __forceinline__ float sel4(v4f d, int r) {
  const float s01 = (r & 1) ? d.y : d.x;
  const float s23 = (r & 1) ? d.w : d.z;
  return (r & 2) ? s23 : s01;
}

__global__ __launch_bounds__(512) void lstm_mfma(
    const float* __restrict__ data, const float* __restrict__ h0,
    const float* __restrict__ c0, const float* __restrict__ W_ih,
    const float* __restrict__ W_hh, const float* __restrict__ b_ih,
    const float* __restrict__ b_hh, const float* __restrict__ W_out,
    const float* __restrict__ b_out, float* __restrict__ out, int T) {
  __shared__ __align__(16) float xs[TMAX];
  __shared__ __align__(16) _Float16 hbuf[2][Hdim];

  const int b = blockIdx.x;
  const int tid = threadIdx.x;
  const int lane = tid & 63;
  const int wv = tid >> 6;  // wave 0..7 owns elements 16wv..16wv+15
  const int p = lane >> 4;  // 0..3
  const int m = lane & 15;  // column id (all D cols identical)
  const int r = m & 3;      // which d-component this lane's tail handles
  const int el = 16 * wv + 4 * p + r;  // my tail element

  // Stage input row (coalesced float4).
  {
    const float4* src = (const float4*)(data + (size_t)b * T);
    float4* dst = (float4*)xs;
    for (int i = tid; i < T / 4; i += 512) dst[i] = src[i];
  }

  constexpr float L2E = 1.44269504088896f;

  // A-frags: gate g -> rows [128g+16wv, 128g+16wv+16), chunk c -> k in
  // [32c,32c+32). Lane holds A[m][32c+8p+j], j=0..7, pre-scaled by Mk(g).
  v8h a[4][4];
#pragma unroll
  for (int g = 0; g < 4; ++g) {
    const int row = 128 * g + 16 * wv + m;
    const float Mr = (g == 2) ? 2.0f * L2E : -L2E;
    const float* wr = W_hh + (size_t)row * Hdim + 8 * p;
#pragma unroll
    for (int c = 0; c < 4; ++c) {
      float4 v0 = ((const float4*)(wr + 32 * c))[0];
      float4 v1 = ((const float4*)(wr + 32 * c))[1];
      a[g][c] = v8h{(_Float16)(Mr * v0.x), (_Float16)(Mr * v0.y),
                    (_Float16)(Mr * v0.z), (_Float16)(Mr * v0.w),
                    (_Float16)(Mr * v1.x), (_Float16)(Mr * v1.y),
                    (_Float16)(Mr * v1.z), (_Float16)(Mr * v1.w)};
    }
  }

  // Bias seeds: acc_init[g].reg = Mk(g)*(b_ih+b_hh) of row 128g+16wv+4p+reg;
  // sourced directly as the C operand of each chain's first MFMA.
  v4f acc_init[4];
#pragma unroll
  for (int g = 0; g < 4; ++g) {
    const float Mr = (g == 2) ? 2.0f * L2E : -L2E;
    const int row = 128 * g + 16 * wv + 4 * p;
    acc_init[g] = v4f{Mr * (b_ih[row + 0] + b_hh[row + 0]),
                      Mr * (b_ih[row + 1] + b_hh[row + 1]),
                      Mr * (b_ih[row + 2] + b_hh[row + 2]),
                      Mr * (b_ih[row + 3] + b_hh[row + 3])};
  }

  // Tail constants: Mk-scaled W_ih for my element, per gate.
  float wih[4];
#pragma unroll
  for (int g = 0; g < 4; ++g) {
    const float Mr = (g == 2) ? 2.0f * L2E : -L2E;
    wih[g] = Mr * W_ih[128 * g + el];
  }

  float cst = c0[(size_t)b * Hdim + el];
  if (tid < 128) hbuf[0][tid] = (_Float16)h0[(size_t)b * Hdim + tid];
  __syncthreads();

  for (int t0 = 0; t0 < T; t0 += 4) {
    const float4 xv = *(const float4*)&xs[t0];  // 4 steps of x, one read
    const float xts[4] = {xv.x, xv.y, xv.z, xv.w};
#pragma unroll
    for (int u = 0; u < 4; ++u) {
      const int t = t0 + u;
      const _Float16* hb = hbuf[t & 1];
      _Float16* hn = hbuf[(t + 1) & 1];
      // B-frags: h chunk c, lane reads h[32c+8p+j] (16-lane broadcast).
      v8h bq[4];
#pragma unroll
      for (int c = 0; c < 4; ++c) bq[c] = *(const v8h*)(hb + 32 * c + 8 * p);
      const float xt = xts[u];

      // Gate pair 1 (i,f): 8 MFMAs, chains interleaved (dep spacing 2).
      v4f d0 = __builtin_amdgcn_mfma_f32_16x16x32_f16(a[0][0], bq[0],
                                                      acc_init[0], 0, 0, 0);
      v4f d1 = __builtin_amdgcn_mfma_f32_16x16x32_f16(a[1][0], bq[0],
                                                      acc_init[1], 0, 0, 0);
#pragma unroll
      for (int c = 1; c < 4; ++c) {
        d0 = __builtin_amdgcn_mfma_f32_16x16x32_f16(a[0][c], bq[c], d0, 0, 0, 0);
        d1 = __builtin_amdgcn_mfma_f32_16x16x32_f16(a[1][c], bq[c], d1, 0, 0, 0);
      }
      // Gate pair 2 (g,o): issued before d0/d1 are consumed.
      v4f d2 = __builtin_amdgcn_mfma_f32_16x16x32_f16(a[2][0], bq[0],
                                                      acc_init[2], 0, 0, 0);
      v4f d3 = __builtin_amdgcn_mfma_f32_16x16x32_f16(a[3][0], bq[0],
                                                      acc_init[3], 0, 0, 0);
#pragma unroll
      for (int c = 1; c < 4; ++c) {
        d2 = __builtin_amdgcn_mfma_f32_16x16x32_f16(a[2][c], bq[c], d2, 0, 0, 0);
        d3 = __builtin_amdgcn_mfma_f32_16x16x32_f16(a[3][c], bq[c], d3, 0, 0, 0);
      }

      // Consume pair 1 first -- its MFMAs retired ~155cy ago; the i/f
      // sigmoid chains issue while d2/d3 drain the matrix pipe.
      const float zi = sel4(d0, r);
      const float zf = sel4(d1, r);
      const float yi =
          __builtin_amdgcn_rcpf(1.0f + exp2_fast(fmaf(xt, wih[0], zi)));
      const float yf =
          __builtin_amdgcn_rcpf(1.0f + exp2_fast(fmaf(xt, wih[1], zf)));

      // Now pair 2.
      const float zg = sel4(d2, r);
      const float zo = sel4(d3, r);
      const float yg = fmaf(
          -2.0f, __builtin_amdgcn_rcpf(1.0f + exp2_fast(fmaf(xt, wih[2], zg))),
          1.0f);
      const float yo =
          __builtin_amdgcn_rcpf(1.0f + exp2_fast(fmaf(xt, wih[3], zo)));

      cst = fmaf(yf, cst, yi * yg);
      const float th = fmaf(
          -2.0f, __builtin_amdgcn_rcpf(1.0f + exp2_fast(cst * (2.0f * L2E))),
          1.0f);
      const float h = yo * th;

      if (m < 4) hn[el] = (_Float16)h;
      __syncthreads();
    }
  }

  // Final linear: out[b] = h_T . W_out + b_out (wave 0).
  if (tid < 64) {
    const _Float16* hf = hbuf[T & 1];
    float sum =
        (float)hf[tid] * W_out[tid] + (float)hf[tid + 64] * W_out[tid + 64];
#pragma unroll
    for (int off = 32; off > 0; off >>= 1) sum += __shfl_down(sum, off, 64);
    if (tid == 0) out[b] = sum + b_out[0];
  }
}

extern "C" void kernel_launch(void* const* d_in, const int* in_sizes, int n_in,
                              void* d_out, int out_size, void* d_ws,
                              size_t ws_size, hipStream_t stream) {
  const float* data = (const float*)d_in[0];
  const float* h0 = (const float*)d_in[1];
  const float* c0 = (const float*)d_in[2];
  const float* W_ih = (const float*)d_in[3];
  const float* W_hh = (const float*)d_in[4];
  const float* b_ih = (const float*)d_in[5];
  const float* b_hh = (const float*)d_in[6];
  const float* W_out = (const float*)d_in[7];
  const float* b_out = (const float*)d_in[8];
  float* out = (float*)d_out;

  const int B = in_sizes[1] / Hdim;  // 64
  const int T = in_sizes[0] / B;     // 4096

  lstm_mfma<<<B, 512, 0, stream>>>(data, h0, c0, W_ih, W_hh, b_ih, b_hh,
                                   W_out, b_out, out, T);
}

// Round 17
// 1734.275 us; speedup vs baseline: 1.1301x; 1.1301x over previous
//
#include <hip/hip_runtime.h>
#include <math.h>

// LSTM persistent kernel, R17: R15 (best: 1681us) + pair-split tail.
// One block per batch (64 blocks), 512 threads = 8 waves; wave wv owns all
// 4 gates of elements 16wv..16wv+15; c-major 4-chain MFMA interleave
// (R16 showed 2-chain spacing starves the matrix pipe); bias as C operand;
// one barrier/step.
//
// R15 model (981 cy/step): CU matrix pipe 518 + per-SIMD VALU 520,
// phase-locked (round-robin MFMA arbitration finishes all waves together,
// tails serialize after). VALU is dominated by 10 transcendentals/lane
// (4 gates x exp+rcp + tanh) = 320 cy/SIMD. R17 uses the unused m&4 column
// redundancy: par0 lanes compute gates i,g; par1 lanes compute f,o (uniform
// code, lane-selected constants); yi*yg crosses par0->par1 via one DPP
// row_shl:4 (full-rate); par1 owns c/tanh/h and the h-write. 10 -> 6
// transcendental issues/lane. All formulas identical -> results
// bit-identical to R15 (absmax must stay exactly 2.441e-4).
constexpr int Hdim = 128;
constexpr int TMAX = 4096;

typedef _Float16 v8h __attribute__((ext_vector_type(8)));
typedef float v4f __attribute__((ext_vector_type(4)));

template <int CTRL>
__device__ __forceinline__ float dppf(float v) {
  return __int_as_float(
      __builtin_amdgcn_update_dpp(0, __float_as_int(v), CTRL, 0xF, 0xF, true));
}

#if __has_builtin(__builtin_amdgcn_exp2f)
__device__ __forceinline__ float exp2_fast(float x) {
  return __builtin_amdgcn_exp2f(x);
}
#else
__device__ __forceinline__ float exp2_fast(float x) {
  return __expf(x * 0.6931471805599453f);
}
#endif

__device__ __forceinline__ float sel4(v4f d, int r) {
  const float s01 = (r & 1) ? d.y : d.x;
  const float s23 = (r & 1) ? d.w : d.z;
  return (r & 2) ? s23 : s01;
}

__global__ __launch_bounds__(512) void lstm_mfma(
    const float* __restrict__ data, const float* __restrict__ h0,
    const float* __restrict__ c0, const float* __restrict__ W_ih,
    const float* __restrict__ W_hh, const float* __restrict__ b_ih,
    const float* __restrict__ b_hh, const float* __restrict__ W_out,
    const float* __restrict__ b_out, float* __restrict__ out, int T) {
  __shared__ __align__(16) float xs[TMAX];
  __shared__ __align__(16) _Float16 hbuf[2][Hdim];

  const int b = blockIdx.x;
  const int tid = threadIdx.x;
  const int lane = tid & 63;
  const int wv = tid >> 6;  // wave 0..7 owns elements 16wv..16wv+15
  const int p = lane >> 4;  // 0..3
  const int m = lane & 15;  // column id (all D cols identical)
  const int r = m & 3;      // d-component select
  const bool par = (m & 4) != 0;  // 0: gates i,g ; 1: gates f,o + c/h owner
  const int el = 16 * wv + 4 * p + r;  // my tail element

  // Stage input row (coalesced float4).
  {
    const float4* src = (const float4*)(data + (size_t)b * T);
    float4* dst = (float4*)xs;
    for (int i = tid; i < T / 4; i += 512) dst[i] = src[i];
  }

  constexpr float L2E = 1.44269504088896f;

  // A-frags: gate g -> rows [128g+16wv, 128g+16wv+16), chunk c -> k in
  // [32c,32c+32). Lane holds A[m][32c+8p+j], j=0..7, pre-scaled by Mk(g).
  v8h a[4][4];
#pragma unroll
  for (int g = 0; g < 4; ++g) {
    const int row = 128 * g + 16 * wv + m;
    const float Mr = (g == 2) ? 2.0f * L2E : -L2E;
    const float* wr = W_hh + (size_t)row * Hdim + 8 * p;
#pragma unroll
    for (int c = 0; c < 4; ++c) {
      float4 v0 = ((const float4*)(wr + 32 * c))[0];
      float4 v1 = ((const float4*)(wr + 32 * c))[1];
      a[g][c] = v8h{(_Float16)(Mr * v0.x), (_Float16)(Mr * v0.y),
                    (_Float16)(Mr * v0.z), (_Float16)(Mr * v0.w),
                    (_Float16)(Mr * v1.x), (_Float16)(Mr * v1.y),
                    (_Float16)(Mr * v1.z), (_Float16)(Mr * v1.w)};
    }
  }

  // Bias seeds: acc_init[g].reg = Mk(g)*(b_ih+b_hh) of row 128g+16wv+4p+reg;
  // sourced directly as the C operand of each chain's first MFMA.
  v4f acc_init[4];
#pragma unroll
  for (int g = 0; g < 4; ++g) {
    const float Mr = (g == 2) ? 2.0f * L2E : -L2E;
    const int row = 128 * g + 16 * wv + 4 * p;
    acc_init[g] = v4f{Mr * (b_ih[row + 0] + b_hh[row + 0]),
                      Mr * (b_ih[row + 1] + b_hh[row + 1]),
                      Mr * (b_ih[row + 2] + b_hh[row + 2]),
                      Mr * (b_ih[row + 3] + b_hh[row + 3])};
  }

  // Pair-split tail constants: gate A = i(0)/f(1), gate B = g(2)/o(3).
  const int gA = par ? 1 : 0;
  const int gB = par ? 3 : 2;
  const float wihA = -L2E * W_ih[128 * gA + el];          // Mk(i)=Mk(f)=-L2E
  const float MrB = par ? -L2E : 2.0f * L2E;
  const float wihB = MrB * W_ih[128 * gB + el];
  const float AsB = par ? 1.0f : -2.0f;  // sigmoid vs tanh form for gate B
  const float BsB = par ? 0.0f : 1.0f;

  float cst = c0[(size_t)b * Hdim + el];  // real chain only on par1 lanes
  if (tid < 128) hbuf[0][tid] = (_Float16)h0[(size_t)b * Hdim + tid];
  __syncthreads();

  for (int t0 = 0; t0 < T; t0 += 4) {
    const float4 xv = *(const float4*)&xs[t0];  // 4 steps of x, one read
    const float xts[4] = {xv.x, xv.y, xv.z, xv.w};
#pragma unroll
    for (int u = 0; u < 4; ++u) {
      const int t = t0 + u;
      const _Float16* hb = hbuf[t & 1];
      _Float16* hn = hbuf[(t + 1) & 1];
      // B-frags: h chunk c, lane reads h[32c+8p+j] (16-lane broadcast).
      v8h bq[4];
#pragma unroll
      for (int c = 0; c < 4; ++c) bq[c] = *(const v8h*)(hb + 32 * c + 8 * p);
      const float xt = xts[u];

      // 4 independent gate chains, c-major (4-chain interleave -- R16
      // proved 2-chain spacing starves the pipe); bias as C on chunk 0.
      v4f d0 = __builtin_amdgcn_mfma_f32_16x16x32_f16(a[0][0], bq[0],
                                                      acc_init[0], 0, 0, 0);
      v4f d1 = __builtin_amdgcn_mfma_f32_16x16x32_f16(a[1][0], bq[0],
                                                      acc_init[1], 0, 0, 0);
      v4f d2 = __builtin_amdgcn_mfma_f32_16x16x32_f16(a[2][0], bq[0],
                                                      acc_init[2], 0, 0, 0);
      v4f d3 = __builtin_amdgcn_mfma_f32_16x16x32_f16(a[3][0], bq[0],
                                                      acc_init[3], 0, 0, 0);
#pragma unroll
      for (int c = 1; c < 4; ++c) {
        d0 = __builtin_amdgcn_mfma_f32_16x16x32_f16(a[0][c], bq[c], d0, 0, 0, 0);
        d1 = __builtin_amdgcn_mfma_f32_16x16x32_f16(a[1][c], bq[c], d1, 0, 0, 0);
        d2 = __builtin_amdgcn_mfma_f32_16x16x32_f16(a[2][c], bq[c], d2, 0, 0, 0);
        d3 = __builtin_amdgcn_mfma_f32_16x16x32_f16(a[3][c], bq[c], d3, 0, 0, 0);
      }

      // Pair-split tail: my two gates only (6 transcendentals vs 10).
      const float zi = sel4(d0, r);
      const float zf = sel4(d1, r);
      const float zg = sel4(d2, r);
      const float zo = sel4(d3, r);
      const float zA = par ? zf : zi;
      const float zB = par ? zo : zg;

      const float yA =
          __builtin_amdgcn_rcpf(1.0f + exp2_fast(fmaf(xt, wihA, zA)));
      const float yB = fmaf(
          AsB, __builtin_amdgcn_rcpf(1.0f + exp2_fast(fmaf(xt, wihB, zB))),
          BsB);

      const float P = yA * yB;        // par0: yi*yg ; par1: unused junk
      const float Pr = dppf<0x104>(P);  // row_shl:4 -> par1 gets yi*yg

      // par1 lanes: c = yf*c + yi*yg ; h = yo*tanh(c). par0: junk (unused).
      cst = fmaf(yA, cst, Pr);
      const float th = fmaf(
          -2.0f, __builtin_amdgcn_rcpf(1.0f + exp2_fast(cst * (2.0f * L2E))),
          1.0f);
      const float h = yB * th;

      if ((m & 12) == 4) hn[el] = (_Float16)h;  // par1, first copy (m=4..7)
      __syncthreads();
    }
  }

  // Final linear: out[b] = h_T . W_out + b_out (wave 0).
  if (tid < 64) {
    const _Float16* hf = hbuf[T & 1];
    float sum =
        (float)hf[tid] * W_out[tid] + (float)hf[tid + 64] * W_out[tid + 64];
#pragma unroll
    for (int off = 32; off > 0; off >>= 1) sum += __shfl_down(sum, off, 64);
    if (tid == 0) out[b] = sum + b_out[0];
  }
}

extern "C" void kernel_launch(void* const* d_in, const int* in_sizes, int n_in,
                              void* d_out, int out_size, void* d_ws,
                              size_t ws_size, hipStream_t stream) {
  const float* data = (const float*)d_in[0];
  const float* h0 = (const float*)d_in[1];
  const float* c0 = (const float*)d_in[2];
  const float* W_ih = (const float*)d_in[3];
  const float* W_hh = (const float*)d_in[4];
  const float* b_ih = (const float*)d_in[5];
  const float* b_hh = (const float*)d_in[6];
  const float* W_out = (const float*)d_in[7];
  const float* b_out = (const float*)d_in[8];
  float* out = (float*)d_out;

  const int B = in_sizes[1] / Hdim;  // 64
  const int T = in_sizes[0] / B;     // 4096

  lstm_mfma<<<B, 512, 0, stream>>>(data, h0, c0, W_ih, W_hh, b_ih, b_hh,
                                   W_out, b_out, out, T);
}

// Round 18
// 1683.976 us; speedup vs baseline: 1.1639x; 1.0299x over previous
//
#include <hip/hip_runtime.h>
#include <math.h>

// LSTM persistent kernel, R18: R15 (best verified: 1681us) + dependency-
// ordered tail. One block per batch (64 blocks), 512 threads = 8 waves;
// wave wv owns all 4 gates of elements 16wv..16wv+15; c-major 4-chain MFMA
// interleave; bias as C operand; one barrier/step.
//
// R13/R16/R17 post-mortems established: wall(981cy) = MFMA pipe (518, CU-
// wide) + EXPOSED SERIAL CHAIN (~460), and VALU-issue cuts don't move the
// wall -- most gate math already hides under the MFMA phase. The exposed
// chain is [last MFMA d3] -> sel -> gate-o -> c/tanh -> h -> write -> bar
// -> ds_read. R18 reorders: gates i,f,g (d0..d2, retire ~60cy before d3)
// feed the c-update + FULL tanh chain BEFORE d3 is touched; only the yo
// sigmoid + final mul remain after the last MFMA (-~110 cy exposed).
// Also: c-state kept pre-scaled by 2*log2e (yg's affine constants absorb
// it) so the exposed tanh entry has no mul.
constexpr int Hdim = 128;
constexpr int TMAX = 4096;

typedef _Float16 v8h __attribute__((ext_vector_type(8)));
typedef float v4f __attribute__((ext_vector_type(4)));

#if __has_builtin(__builtin_amdgcn_exp2f)
__device__ __forceinline__ float exp2_fast(float x) {
  return __builtin_amdgcn_exp2f(x);
}
#else
__device__ __forceinline__ float exp2_fast(float x) {
  return __expf(x * 0.6931471805599453f);
}
#endif

__device__ __forceinline__ float sel4(v4f d, int r) {
  const float s01 = (r & 1) ? d.y : d.x;
  const float s23 = (r & 1) ? d.w : d.z;
  return (r & 2) ? s23 : s01;
}

__global__ __launch_bounds__(512) void lstm_mfma(
    const float* __restrict__ data, const float* __restrict__ h0,
    const float* __restrict__ c0, const float* __restrict__ W_ih,
    const float* __restrict__ W_hh, const float* __restrict__ b_ih,
    const float* __restrict__ b_hh, const float* __restrict__ W_out,
    const float* __restrict__ b_out, float* __restrict__ out, int T) {
  __shared__ __align__(16) float xs[TMAX];
  __shared__ __align__(16) _Float16 hbuf[2][Hdim];

  const int b = blockIdx.x;
  const int tid = threadIdx.x;
  const int lane = tid & 63;
  const int wv = tid >> 6;  // wave 0..7 owns elements 16wv..16wv+15
  const int p = lane >> 4;  // 0..3
  const int m = lane & 15;  // column id (all D cols identical)
  const int r = m & 3;      // d-component select
  const int el = 16 * wv + 4 * p + r;  // my tail element

  // Stage input row (coalesced float4).
  {
    const float4* src = (const float4*)(data + (size_t)b * T);
    float4* dst = (float4*)xs;
    for (int i = tid; i < T / 4; i += 512) dst[i] = src[i];
  }

  constexpr float L2E = 1.44269504088896f;

  // A-frags: gate g -> rows [128g+16wv, 128g+16wv+16), chunk c -> k in
  // [32c,32c+32). Lane holds A[m][32c+8p+j], j=0..7, pre-scaled by Mk(g).
  v8h a[4][4];
#pragma unroll
  for (int g = 0; g < 4; ++g) {
    const int row = 128 * g + 16 * wv + m;
    const float Mr = (g == 2) ? 2.0f * L2E : -L2E;
    const float* wr = W_hh + (size_t)row * Hdim + 8 * p;
#pragma unroll
    for (int c = 0; c < 4; ++c) {
      float4 v0 = ((const float4*)(wr + 32 * c))[0];
      float4 v1 = ((const float4*)(wr + 32 * c))[1];
      a[g][c] = v8h{(_Float16)(Mr * v0.x), (_Float16)(Mr * v0.y),
                    (_Float16)(Mr * v0.z), (_Float16)(Mr * v0.w),
                    (_Float16)(Mr * v1.x), (_Float16)(Mr * v1.y),
                    (_Float16)(Mr * v1.z), (_Float16)(Mr * v1.w)};
    }
  }

  // Bias seeds: acc_init[g].reg = Mk(g)*(b_ih+b_hh) of row 128g+16wv+4p+reg;
  // sourced directly as the C operand of each chain's first MFMA.
  v4f acc_init[4];
#pragma unroll
  for (int g = 0; g < 4; ++g) {
    const float Mr = (g == 2) ? 2.0f * L2E : -L2E;
    const int row = 128 * g + 16 * wv + 4 * p;
    acc_init[g] = v4f{Mr * (b_ih[row + 0] + b_hh[row + 0]),
                      Mr * (b_ih[row + 1] + b_hh[row + 1]),
                      Mr * (b_ih[row + 2] + b_hh[row + 2]),
                      Mr * (b_ih[row + 3] + b_hh[row + 3])};
  }

  // Tail constants: Mk-scaled W_ih for my element, per gate.
  float wih[4];
#pragma unroll
  for (int g = 0; g < 4; ++g) {
    const float Mr = (g == 2) ? 2.0f * L2E : -L2E;
    wih[g] = Mr * W_ih[128 * g + el];
  }

  // c-state pre-scaled by 2*L2E: tanh chain entry needs no mul.
  constexpr float C2 = 2.0f * L2E;
  float cs = C2 * c0[(size_t)b * Hdim + el];
  if (tid < 128) hbuf[0][tid] = (_Float16)h0[(size_t)b * Hdim + tid];
  __syncthreads();

  for (int t0 = 0; t0 < T; t0 += 4) {
    const float4 xv = *(const float4*)&xs[t0];  // 4 steps of x, one read
    const float xts[4] = {xv.x, xv.y, xv.z, xv.w};
#pragma unroll
    for (int u = 0; u < 4; ++u) {
      const int t = t0 + u;
      const _Float16* hb = hbuf[t & 1];
      _Float16* hn = hbuf[(t + 1) & 1];
      // B-frags: h chunk c, lane reads h[32c+8p+j] (16-lane broadcast).
      v8h bq[4];
#pragma unroll
      for (int c = 0; c < 4; ++c) bq[c] = *(const v8h*)(hb + 32 * c + 8 * p);
      const float xt = xts[u];

      // 4 independent gate chains, c-major (order i,f,g,o -> d3=o retires
      // LAST; everything except the yo chain runs before it drains).
      v4f d0 = __builtin_amdgcn_mfma_f32_16x16x32_f16(a[0][0], bq[0],
                                                      acc_init[0], 0, 0, 0);
      v4f d1 = __builtin_amdgcn_mfma_f32_16x16x32_f16(a[1][0], bq[0],
                                                      acc_init[1], 0, 0, 0);
      v4f d2 = __builtin_amdgcn_mfma_f32_16x16x32_f16(a[2][0], bq[0],
                                                      acc_init[2], 0, 0, 0);
      v4f d3 = __builtin_amdgcn_mfma_f32_16x16x32_f16(a[3][0], bq[0],
                                                      acc_init[3], 0, 0, 0);
#pragma unroll
      for (int c = 1; c < 4; ++c) {
        d0 = __builtin_amdgcn_mfma_f32_16x16x32_f16(a[0][c], bq[c], d0, 0, 0, 0);
        d1 = __builtin_amdgcn_mfma_f32_16x16x32_f16(a[1][c], bq[c], d1, 0, 0, 0);
        d2 = __builtin_amdgcn_mfma_f32_16x16x32_f16(a[2][c], bq[c], d2, 0, 0, 0);
        d3 = __builtin_amdgcn_mfma_f32_16x16x32_f16(a[3][c], bq[c], d3, 0, 0, 0);
      }

      // Phase 1 (depends only on d0..d2, which retire before d3): gates
      // i,f,g; c-update; full tanh chain.
      const float zi = sel4(d0, r);
      const float zf = sel4(d1, r);
      const float zg = sel4(d2, r);
      const float yi =
          __builtin_amdgcn_rcpf(1.0f + exp2_fast(fmaf(xt, wih[0], zi)));
      const float yf =
          __builtin_amdgcn_rcpf(1.0f + exp2_fast(fmaf(xt, wih[1], zf)));
      // yg pre-scaled by C2: C2*tanh = fmaf(-2*C2, rcp, C2).
      const float ygs = fmaf(
          -2.0f * C2,
          __builtin_amdgcn_rcpf(1.0f + exp2_fast(fmaf(xt, wih[2], zg))), C2);
      cs = fmaf(yf, cs, yi * ygs);  // cs = C2 * c
      const float th = fmaf(
          -2.0f, __builtin_amdgcn_rcpf(1.0f + exp2_fast(cs)), 1.0f);

      // Phase 2 (the only post-d3 work): yo chain + final mul + write.
      const float zo = sel4(d3, r);
      const float yo =
          __builtin_amdgcn_rcpf(1.0f + exp2_fast(fmaf(xt, wih[3], zo)));
      const float h = yo * th;

      if (m < 4) hn[el] = (_Float16)h;
      __syncthreads();
    }
  }

  // Final linear: out[b] = h_T . W_out + b_out (wave 0).
  if (tid < 64) {
    const _Float16* hf = hbuf[T & 1];
    float sum =
        (float)hf[tid] * W_out[tid] + (float)hf[tid + 64] * W_out[tid + 64];
#pragma unroll
    for (int off = 32; off > 0; off >>= 1) sum += __shfl_down(sum, off, 64);
    if (tid == 0) out[b] = sum + b_out[0];
  }
}

extern "C" void kernel_launch(void* const* d_in, const int* in_sizes, int n_in,
                              void* d_out, int out_size, void* d_ws,
                              size_t ws_size, hipStream_t stream) {
  const float* data = (const float*)d_in[0];
  const float* h0 = (const float*)d_in[1];
  const float* c0 = (const float*)d_in[2];
  const float* W_ih = (const float*)d_in[3];
  const float* W_hh = (const float*)d_in[4];
  const float* b_ih = (const float*)d_in[5];
  const float* b_hh = (const float*)d_in[6];
  const float* W_out = (const float*)d_in[7];
  const float* b_out = (const float*)d_in[8];
  float* out = (float*)d_out;

  const int B = in_sizes[1] / Hdim;  // 64
  const int T = in_sizes[0] / B;     // 4096

  lstm_mfma<<<B, 512, 0, stream>>>(data, h0, c0, W_ih, W_hh, b_ih, b_hh,
                                   W_out, b_out, out, T);
}